// Round 8
// baseline (145.799 us; speedup 1.0000x reference)
//
#include <hip/hip_runtime.h>
#include <hip/hip_bf16.h>

// RNN cell: out[B,N] = tanh( concat(x,hidden)[B,K] @ W^T[K,N] + b[N] )
// M=16384, N=1024, K=2048, fp32 in/out.
// Pass 1: fp32->bf16 cvt+concat into ws (XHb[M][2048], Wb[N][2048]).
// Pass 2: 256x256 bf16 MFMA GEMM, A staged in LDS via global_load_lds
//   (swizzled source), B loaded DIRECTLY from L2 into registers (Wb panel
//   is 512 KB per XCD-column -> L2-resident). One __syncthreads per K-tile;
//   next tile's A-stage issued at tile top so the sync's vmcnt(0) drain is
//   ~2400 cyc after issue (HBM latency fully hidden under MFMA).

typedef __bf16 bf16_t;
typedef __bf16 bf16x8 __attribute__((ext_vector_type(8)));
typedef float  f32x4  __attribute__((ext_vector_type(4)));

#define M_GLOBAL 16384
#define N_GLOBAL 1024
#define K_GLOBAL 2048
#define IN_STRIDE 1024
#define NT 32

__device__ __forceinline__ float fast_tanh(float v) {
    float e = __expf(2.0f * v);
    return 1.0f - 2.0f * __builtin_amdgcn_rcpf(e + 1.0f);
}

// ---------------------------------------------------------------------------
// Pass 1: cvt + concat (runs at BW ceiling; L3-warm on replay).
// ---------------------------------------------------------------------------
#define XH_UNITS ((long long)M_GLOBAL * K_GLOBAL / 8)
#define W_UNITS  ((long long)N_GLOBAL * K_GLOBAL / 8)

__global__ __launch_bounds__(256)
void cvt_pass(const float* __restrict__ x, const float* __restrict__ h,
              const float* __restrict__ W,
              bf16_t* __restrict__ XHb, bf16_t* __restrict__ Wb)
{
    const long long total = XH_UNITS + W_UNITS;
    for (long long u = (long long)blockIdx.x * 256 + threadIdx.x; u < total;
         u += (long long)gridDim.x * 256) {
        const float* src;
        bf16_t* dst;
        if (u < XH_UNITS) {
            const long long e = u * 8;
            const int row = (int)(e >> 11);
            const int col = (int)(e & 2047);
            src = (col < 1024) ? (x + (long long)row * IN_STRIDE + col)
                               : (h + (long long)row * IN_STRIDE + (col - 1024));
            dst = XHb + e;
        } else {
            const long long e = (u - XH_UNITS) * 8;
            src = W + e;
            dst = Wb + e;
        }
        const float4 v0 = *(const float4*)src;
        const float4 v1 = *(const float4*)(src + 4);
        bf16x8 o;
        o[0] = (bf16_t)v0.x; o[1] = (bf16_t)v0.y;
        o[2] = (bf16_t)v0.z; o[3] = (bf16_t)v0.w;
        o[4] = (bf16_t)v1.x; o[5] = (bf16_t)v1.y;
        o[6] = (bf16_t)v1.z; o[7] = (bf16_t)v1.w;
        *(bf16x8*)dst = o;
    }
}

// ---------------------------------------------------------------------------
// Pass 2: B-direct GEMM. 512 threads = 8 waves (2M x 4N), per-wave 128x64.
// LDS: A only, 2 dbuf x 256x64 bf16 = 64 KB. Swizzle (verified r7, 0
// conflicts): LDS slot s of row r holds global k-slot s^(r&7); applied on
// the global SOURCE (gload_lds writes linearly, rule 21) and on ds_read.
// ---------------------------------------------------------------------------
__device__ __forceinline__ void gload_lds16(const bf16_t* g, bf16_t* l) {
    __builtin_amdgcn_global_load_lds(
        (const __attribute__((address_space(1))) void*)g,
        (__attribute__((address_space(3))) void*)l, 16, 0, 0);
}

__global__ __launch_bounds__(512, 2)
void gemm_bd(const bf16_t* __restrict__ XHb, const bf16_t* __restrict__ Wb,
             const float* __restrict__ bias, float* __restrict__ out)
{
    __shared__ __align__(16) bf16_t lds[2 * 16384];   // 64 KB, A only

    const int tid = threadIdx.x;
    // XCD-aware bijective remap (grid=256 = 8 XCDs x 32): one n-panel per
    // 2 XCDs -> 512 KB Wb slice L2-resident; m-panels shared via L3.
    const int xcd = blockIdx.x & 7;
    const int lid = xcd * 32 + (blockIdx.x >> 3);
    const int bm  = (lid & 63) * 256;
    const int bn  = (lid >> 6) * 256;

    const int lane = tid & 63;
    const int wid  = tid >> 6;
    const int wm = wid >> 2;          // 0..1 (M half)
    const int wn = wid & 3;           // 0..3 (N quarter)
    const int lr = lane & 15;
    const int lk = lane >> 4;
    const int s7 = lr & 7;

    // staging: each wave stages 2 chunks of 8 rows per 128-row half (4
    // gload_lds16/thread per tile). Lane: row srow, source col pre-swizzled.
    const int srow = lane >> 3;
    const int scol = ((lane & 7) ^ srow) * 8;
    const int c0   = wid * 2;
    const bf16_t* aS = XHb + (size_t)(bm + c0 * 8 + srow) * K_GLOBAL + scol;

    // B source: row = output col (Wb is [N][K]); frag (nf,kk) of tile t at
    // bS + nf*16*K + t*64 + kk*32.
    const bf16_t* bS = Wb + (size_t)(bn + wn * 64 + lr) * K_GLOBAL + lk * 8;

    // A frag base: row R = wm*128 + mf*16 + lr -> addr R*64; R&7 == s7.
    const int abase = (wm * 128 + lr) * 64;

    f32x4 acc[8][4];
#pragma unroll
    for (int i = 0; i < 8; ++i)
#pragma unroll
        for (int j = 0; j < 4; ++j)
            acc[i][j] = (f32x4){0.f, 0.f, 0.f, 0.f};

#define STAGE_A(T, D) {                                                       \
    _Pragma("unroll")                                                         \
    for (int p_ = 0; p_ < 2; ++p_) {                                          \
        _Pragma("unroll")                                                     \
        for (int ch_ = 0; ch_ < 2; ++ch_) {                                   \
            gload_lds16(aS + (size_t)(p_ * 128 + ch_ * 8) * K_GLOBAL + (T) * 64, \
                        lds + (D) * 16384 + p_ * 8192 + (c0 + ch_) * 512);    \
        }                                                                     \
    }                                                                         \
}

    // prologue: stage T0 -> dbuf0
    STAGE_A(0, 0);
    __syncthreads();

    for (int t = 0; t < NT; ++t) {
        const int d = t & 1;

        // ---- B frags for tile t: 8 x 16B from L2 (compiler-tracked waits)
        bf16x8 bq[4][2];
#pragma unroll
        for (int nf = 0; nf < 4; ++nf)
#pragma unroll
            for (int kk = 0; kk < 2; ++kk)
                bq[nf][kk] = *(const bf16x8*)(
                    bS + (size_t)nf * 16 * K_GLOBAL + t * 64 + kk * 32);

        // pin order: B loads issue BEFORE stage loads, so the compiler's
        // wait-for-B is vmcnt(4) (stages stay in flight), not a stage drain.
        __builtin_amdgcn_sched_barrier(0);

        // ---- issue next tile's A-stage; lands under this tile's MFMAs,
        // drained by the end-of-tile __syncthreads ~2400 cyc later.
        if (t + 1 < NT) STAGE_A(t + 1, d ^ 1);

        // ---- compute: 16 swizzled ds_read_b128 + 64 MFMA
        const int dbase = d * 16384 + abase;
#pragma unroll
        for (int kk = 0; kk < 2; ++kk) {
            const int sl = ((kk * 4 + lk) ^ s7) * 8;
#pragma unroll
            for (int mf = 0; mf < 8; ++mf) {
                bf16x8 af = *(const bf16x8*)(lds + dbase + mf * 1024 + sl);
#pragma unroll
                for (int nf = 0; nf < 4; ++nf)
                    acc[mf][nf] = __builtin_amdgcn_mfma_f32_16x16x32_bf16(
                        af, bq[nf][kk], acc[mf][nf], 0, 0, 0);
            }
        }

        // one barrier per K-tile: drains stage loads (long since landed) and
        // protects dbuf d from being restaged while still being read.
        __syncthreads();
    }
#undef STAGE_A

    // ---- epilogue: bias + tanh, fp32 store.
    // C/D layout: col = lane&15, row = (lane>>4)*4 + reg (verified r1-r7).
    float bv[4];
#pragma unroll
    for (int nf = 0; nf < 4; ++nf)
        bv[nf] = bias[bn + wn * 64 + nf * 16 + lr];
#pragma unroll
    for (int mf = 0; mf < 8; ++mf) {
#pragma unroll
        for (int nf = 0; nf < 4; ++nf) {
            const int col = bn + wn * 64 + nf * 16 + lr;
#pragma unroll
            for (int r = 0; r < 4; ++r) {
                const int row = bm + wm * 128 + mf * 16 + lk * 4 + r;
                out[(size_t)row * N_GLOBAL + col] = fast_tanh(acc[mf][nf][r] + bv[nf]);
            }
        }
    }
}

// ---------------------------------------------------------------------------
// Fallback (ws too small): round-3 verified fused kernel (~169 us).
// ---------------------------------------------------------------------------
#define FNT 32
__global__ __launch_bounds__(256, 2)
void rnncell_fused(const float* __restrict__ x, const float* __restrict__ h,
                   const float* __restrict__ W, const float* __restrict__ bias,
                   float* __restrict__ out)
{
    __shared__ __align__(16) bf16_t As[2][128 * 64];
    __shared__ __align__(16) bf16_t Bs[2][128 * 64];

    const int tid = threadIdx.x;
    const int bid = blockIdx.x;
    const int bm = (bid >> 3) * 128;
    const int bn = (bid & 7) * 128;

    const int lane = tid & 63;
    const int wid  = tid >> 6;
    const int wr = (wid >> 1) * 64;
    const int wc = (wid & 1) * 64;
    const int lr = lane & 15;
    const int lk = lane >> 4;

    const int row0 = tid >> 3;
    const int sl0  = tid & 7;

    f32x4 acc[4][4];
#pragma unroll
    for (int i = 0; i < 4; ++i)
#pragma unroll
        for (int j = 0; j < 4; ++j)
            acc[i][j] = (f32x4){0.f, 0.f, 0.f, 0.f};

    float4 la[4][2], lb[4][2];

#define F_LOAD_A(T) do {                                                      \
    const int k0_ = (T) * 64;                                                 \
    const float* sA_ = (k0_ < 1024)                                           \
        ? (x + (size_t)bm * IN_STRIDE + k0_)                                  \
        : (h + (size_t)bm * IN_STRIDE + (k0_ - 1024));                        \
    _Pragma("unroll")                                                         \
    for (int i_ = 0; i_ < 4; ++i_) {                                          \
        const float* pa_ = sA_ + (size_t)(row0 + i_ * 32) * IN_STRIDE + sl0 * 8; \
        la[i_][0] = *(const float4*)(pa_);                                    \
        la[i_][1] = *(const float4*)(pa_ + 4);                                \
    }                                                                         \
} while (0)

#define F_LOAD_B(T) do {                                                      \
    const float* sB_ = W + (size_t)bn * K_GLOBAL + (T) * 64;                  \
    _Pragma("unroll")                                                         \
    for (int i_ = 0; i_ < 4; ++i_) {                                          \
        const float* pb_ = sB_ + (size_t)(row0 + i_ * 32) * K_GLOBAL + sl0 * 8; \
        lb[i_][0] = *(const float4*)(pb_);                                    \
        lb[i_][1] = *(const float4*)(pb_ + 4);                                \
    }                                                                         \
} while (0)

    F_LOAD_A(0);
    F_LOAD_B(0);

    for (int t = 0; t < FNT; ++t) {
        bf16_t* __restrict__ Ab = As[t & 1];
        bf16_t* __restrict__ Bb = Bs[t & 1];

#pragma unroll
        for (int i = 0; i < 4; ++i) {
            const int row = row0 + i * 32;
            const int ssl = sl0 ^ (row & 7);
            bf16x8 va;
            va[0] = (bf16_t)la[i][0].x; va[1] = (bf16_t)la[i][0].y;
            va[2] = (bf16_t)la[i][0].z; va[3] = (bf16_t)la[i][0].w;
            va[4] = (bf16_t)la[i][1].x; va[5] = (bf16_t)la[i][1].y;
            va[6] = (bf16_t)la[i][1].z; va[7] = (bf16_t)la[i][1].w;
            *(bf16x8*)(Ab + row * 64 + ssl * 8) = va;
        }
#pragma unroll
        for (int i = 0; i < 4; ++i) {
            const int row = row0 + i * 32;
            const int ssl = sl0 ^ (row & 7);
            bf16x8 vb;
            vb[0] = (bf16_t)lb[i][0].x; vb[1] = (bf16_t)lb[i][0].y;
            vb[2] = (bf16_t)lb[i][0].z; vb[3] = (bf16_t)lb[i][0].w;
            vb[4] = (bf16_t)lb[i][1].x; vb[5] = (bf16_t)lb[i][1].y;
            vb[6] = (bf16_t)lb[i][1].z; vb[7] = (bf16_t)lb[i][1].w;
            *(bf16x8*)(Bb + row * 64 + ssl * 8) = vb;
        }

        __syncthreads();

        if (t + 1 < FNT) F_LOAD_A(t + 1);

#pragma unroll
        for (int kk = 0; kk < 2; ++kk) {
            bf16x8 af[4], bfr[4];
#pragma unroll
            for (int mf = 0; mf < 4; ++mf) {
                const int row = wr + mf * 16 + lr;
                const int sl  = (kk * 4 + lk) ^ (row & 7);
                af[mf] = *(const bf16x8*)(Ab + row * 64 + sl * 8);
            }
#pragma unroll
            for (int nf = 0; nf < 4; ++nf) {
                const int row = wc + nf * 16 + lr;
                const int sl  = (kk * 4 + lk) ^ (row & 7);
                bfr[nf] = *(const bf16x8*)(Bb + row * 64 + sl * 8);
            }
#pragma unroll
            for (int mf = 0; mf < 4; ++mf)
#pragma unroll
                for (int nf = 0; nf < 4; ++nf)
                    acc[mf][nf] = __builtin_amdgcn_mfma_f32_16x16x32_bf16(
                        af[mf], bfr[nf], acc[mf][nf], 0, 0, 0);
        }

        if (t + 1 < FNT) F_LOAD_B(t + 1);
    }
#undef F_LOAD_A
#undef F_LOAD_B

    float bv[4];
#pragma unroll
    for (int nf = 0; nf < 4; ++nf)
        bv[nf] = bias[bn + wc + nf * 16 + lr];
#pragma unroll
    for (int mf = 0; mf < 4; ++mf) {
#pragma unroll
        for (int nf = 0; nf < 4; ++nf) {
            const int col = bn + wc + nf * 16 + lr;
#pragma unroll
            for (int r = 0; r < 4; ++r) {
                const int row = bm + wr + mf * 16 + lk * 4 + r;
                out[(size_t)row * N_GLOBAL + col] = fast_tanh(acc[mf][nf][r] + bv[nf]);
            }
        }
    }
}

extern "C" void kernel_launch(void* const* d_in, const int* in_sizes, int n_in,
                              void* d_out, int out_size, void* d_ws, size_t ws_size,
                              hipStream_t stream) {
    (void)in_sizes; (void)n_in; (void)out_size;
    const float* x = (const float*)d_in[0];
    const float* h = (const float*)d_in[1];
    const float* W = (const float*)d_in[2];
    const float* b = (const float*)d_in[3];
    float* out = (float*)d_out;

    const size_t need = ((size_t)M_GLOBAL + N_GLOBAL) * K_GLOBAL * sizeof(bf16_t);
    if (ws_size >= need) {
        bf16_t* XHb = (bf16_t*)d_ws;
        bf16_t* Wb  = XHb + (size_t)M_GLOBAL * K_GLOBAL;
        cvt_pass<<<2048, 256, 0, stream>>>(x, h, W, XHb, Wb);
        gemm_bd<<<256, 512, 0, stream>>>(XHb, Wb, b, out);
    } else {
        rnncell_fused<<<1024, 256, 0, stream>>>(x, h, W, b, out);
    }
}

// Round 9
// 102.576 us; speedup vs baseline: 1.4214x; 1.4214x over previous
//
#include <hip/hip_runtime.h>
#include <hip/hip_bf16.h>

// RNN cell: out[B,N] = tanh( concat(x,hidden)[B,K] @ W^T[K,N] + b[N] )
// M=16384, N=1024, K=2048, fp32 in/out.
// Pass 1: fp32->bf16 cvt+concat into ws. Pass 2: 256x256 8-phase GEMM,
// kk-major phase grouping (4A+4B or 4A ds_reads/phase, 16 independent
// MFMA/phase), counted vmcnt(2) gates, setprio. Round-8 B-direct reverted.

typedef __bf16 bf16_t;
typedef __bf16 bf16x8 __attribute__((ext_vector_type(8)));
typedef float  f32x4  __attribute__((ext_vector_type(4)));

#define M_GLOBAL 16384
#define N_GLOBAL 1024
#define K_GLOBAL 2048
#define IN_STRIDE 1024
#define NT 32

__device__ __forceinline__ float fast_tanh(float v) {
    float e = __expf(2.0f * v);
    return 1.0f - 2.0f * __builtin_amdgcn_rcpf(e + 1.0f);
}

// ---------------------------------------------------------------------------
// Pass 1: cvt + concat (~6.4 TB/s; L3-warm on replay ~8.5us).
// ---------------------------------------------------------------------------
#define XH_UNITS ((long long)M_GLOBAL * K_GLOBAL / 8)
#define W_UNITS  ((long long)N_GLOBAL * K_GLOBAL / 8)

__global__ __launch_bounds__(256)
void cvt_pass(const float* __restrict__ x, const float* __restrict__ h,
              const float* __restrict__ W,
              bf16_t* __restrict__ XHb, bf16_t* __restrict__ Wb)
{
    const long long total = XH_UNITS + W_UNITS;
    for (long long u = (long long)blockIdx.x * 256 + threadIdx.x; u < total;
         u += (long long)gridDim.x * 256) {
        const float* src;
        bf16_t* dst;
        if (u < XH_UNITS) {
            const long long e = u * 8;
            const int row = (int)(e >> 11);
            const int col = (int)(e & 2047);
            src = (col < 1024) ? (x + (long long)row * IN_STRIDE + col)
                               : (h + (long long)row * IN_STRIDE + (col - 1024));
            dst = XHb + e;
        } else {
            const long long e = (u - XH_UNITS) * 8;
            src = W + e;
            dst = Wb + e;
        }
        const float4 v0 = *(const float4*)src;
        const float4 v1 = *(const float4*)(src + 4);
        bf16x8 o;
        o[0] = (bf16_t)v0.x; o[1] = (bf16_t)v0.y;
        o[2] = (bf16_t)v0.z; o[3] = (bf16_t)v0.w;
        o[4] = (bf16_t)v1.x; o[5] = (bf16_t)v1.y;
        o[6] = (bf16_t)v1.z; o[7] = (bf16_t)v1.w;
        *(bf16x8*)dst = o;
    }
}

// ---------------------------------------------------------------------------
// Pass 2: 256x256 8-phase GEMM, kk-major phases.
// 512 threads = 8 waves (2M x 4N), per-wave output 128x64. BK=64.
// LDS: 2 dbuf x {A0,A1,B0,B1} 128x64 halves (16 KB each) = 128 KB.
// Swizzle (0 conflicts, r7-verified): slot s of row r holds k-slot s^(r&7);
// applied on global SOURCE (gload_lds writes linearly) and on ds_read.
//
// Phase = one k-slice (kk) x one mf-half (M0): 16 INDEPENDENT MFMAs.
// ds_reads/phase: 4 A (+4 B on kk-entry phases; bq regs reused next phase).
//
// Stage slots per iter i (T1=2i+1, T2=2i+2, T3=2i+3), gates VM2 @ph4, ph8:
//  ph1: T1.A0->d1, T1.B1->d1   ph2: T1.A1->d1   ph3: --
//  ph4: T2.B0->d0 [VM2]        ph5: T2.B1->d0   ph6: T2.A0->d0
//  ph7: T2.A1->d0              ph8: T3.B0->d1 [VM2]
// RAW: in-flight after ph4-gate = T2.B0 only (first read ph1 next iter,
//   drained by ph8-gate); after ph8-gate = T3.B0 only (first read ph5 next
//   iter, drained by next ph4-gate). All other stages drain >=2 phases
//   before first read.  WAR: every stage target's last reader is >=1
//   barrier-pair earlier (d_x.B read only at its tile's kk-entry phases
//   ph1/ph3 resp. ph5/ph7; d_x.A read ph1-4 resp. ph5-8).
// ---------------------------------------------------------------------------
__device__ __forceinline__ void gload_lds16(const bf16_t* g, bf16_t* l) {
    __builtin_amdgcn_global_load_lds(
        (const __attribute__((address_space(1))) void*)g,
        (__attribute__((address_space(3))) void*)l, 16, 0, 0);
}

__global__ __launch_bounds__(512, 2)
void gemm8p(const bf16_t* __restrict__ XHb, const bf16_t* __restrict__ Wb,
            const float* __restrict__ bias, float* __restrict__ out)
{
    __shared__ __align__(16) bf16_t lds[2 * 32768];   // 128 KB

    const int tid = threadIdx.x;
    // XCD-aware bijective remap (grid=256 = 8 XCDs x 32): one n-panel per
    // 2 XCDs -> 512 KB Wb slice L2-resident; m-panels shared via L3.
    const int xcd  = blockIdx.x & 7;
    const int lid  = xcd * 32 + (blockIdx.x >> 3);
    const int bm   = (lid & 63) * 256;
    const int bn   = (lid >> 6) * 256;

    const int lane = tid & 63;
    const int wid  = tid >> 6;
    const int wm = wid >> 2;          // 0..1 (M half)
    const int wn = wid & 3;           // 0..3 (N quarter)
    const int lr = lane & 15;
    const int lk = lane >> 4;
    const int s7 = lr & 7;

    // staging: half-tile = 128 rows x 64 cols; wave stages 2 chunks of 8
    // rows; lane covers row srow, source col pre-swizzled.
    const int srow = lane >> 3;
    const int scol = ((lane & 7) ^ srow) * 8;
    const int c0   = wid * 2;
    const bf16_t* aS = XHb + (size_t)(bm + c0 * 8 + srow) * K_GLOBAL + scol;
    const bf16_t* bS = Wb  + (size_t)(bn + c0 * 8 + srow) * K_GLOBAL + scol;

    // frag-read bases (elems): parts A0,A1,B0,B1 at part*8192 within dbuf.
    const int aRd = wm * 8192 + lr * 64;
    const int bRd = (2 + (wn >> 1)) * 8192 + ((wn & 1) * 64 + lr) * 64;

    f32x4 acc[8][4];
#pragma unroll
    for (int i = 0; i < 8; ++i)
#pragma unroll
        for (int j = 0; j < 4; ++j)
            acc[i][j] = (f32x4){0.f, 0.f, 0.f, 0.f};

#define STAGE(D, PART, T) {                                                   \
    const bf16_t* g_ = (((PART) < 2) ? aS : bS)                               \
        + (size_t)(((PART) & 1) * 128) * K_GLOBAL + (T) * 64;                 \
    bf16_t* l_ = lds + (D) * 32768 + (PART) * 8192 + c0 * 512;                \
    gload_lds16(g_, l_);                                                      \
    gload_lds16(g_ + (size_t)8 * K_GLOBAL, l_ + 512);                         \
}

#define BAR() { asm volatile("" ::: "memory");                                \
                __builtin_amdgcn_s_barrier();                                 \
                asm volatile("" ::: "memory"); }
#define VM2() asm volatile("s_waitcnt vmcnt(2)" ::: "memory")
#define VM0() asm volatile("s_waitcnt vmcnt(0)" ::: "memory")

// One phase: kk-slice SLK (0 or 4), mf-half M0 (0 or 4). Reads 4 A-frags
// (+4 B-frags into persistent bq if READB), stages, barrier, lgkm drain
// (+sched fence, rule 18), setprio-wrapped 16 independent MFMA.
#define PHASE(DB, SLK, M0, READB, ...) {                                      \
    const int dbo_ = (DB) * 32768;                                            \
    const int sl_  = (((SLK) + lk) ^ s7) * 8;                                 \
    if (READB) {                                                              \
        _Pragma("unroll")                                                     \
        for (int nf_ = 0; nf_ < 4; ++nf_)                                     \
            bq[nf_] = *(const bf16x8*)(lds + dbo_ + bRd + nf_ * 1024 + sl_);  \
    }                                                                         \
    bf16x8 a0_ = *(const bf16x8*)(lds + dbo_ + aRd + ((M0) + 0) * 1024 + sl_); \
    bf16x8 a1_ = *(const bf16x8*)(lds + dbo_ + aRd + ((M0) + 1) * 1024 + sl_); \
    bf16x8 a2_ = *(const bf16x8*)(lds + dbo_ + aRd + ((M0) + 2) * 1024 + sl_); \
    bf16x8 a3_ = *(const bf16x8*)(lds + dbo_ + aRd + ((M0) + 3) * 1024 + sl_); \
    __VA_ARGS__;                                                              \
    asm volatile("" ::: "memory");                                            \
    __builtin_amdgcn_s_barrier();                                             \
    asm volatile("s_waitcnt lgkmcnt(0)" ::: "memory");                        \
    __builtin_amdgcn_sched_barrier(0);                                        \
    __builtin_amdgcn_s_setprio(1);                                            \
    _Pragma("unroll")                                                         \
    for (int nf_ = 0; nf_ < 4; ++nf_) {                                       \
        acc[(M0) + 0][nf_] = __builtin_amdgcn_mfma_f32_16x16x32_bf16(         \
            a0_, bq[nf_], acc[(M0) + 0][nf_], 0, 0, 0);                       \
        acc[(M0) + 1][nf_] = __builtin_amdgcn_mfma_f32_16x16x32_bf16(         \
            a1_, bq[nf_], acc[(M0) + 1][nf_], 0, 0, 0);                       \
        acc[(M0) + 2][nf_] = __builtin_amdgcn_mfma_f32_16x16x32_bf16(         \
            a2_, bq[nf_], acc[(M0) + 2][nf_], 0, 0, 0);                       \
        acc[(M0) + 3][nf_] = __builtin_amdgcn_mfma_f32_16x16x32_bf16(         \
            a3_, bq[nf_], acc[(M0) + 3][nf_], 0, 0, 0);                       \
    }                                                                         \
    __builtin_amdgcn_s_setprio(0);                                            \
}

    bf16x8 bq[4];

    // ---- prologue: T0 all 4 halves -> d0; T1.B0 -> d1 (10 loads).
    STAGE(0, 0, 0); STAGE(0, 1, 0); STAGE(0, 2, 0); STAGE(0, 3, 0);
    STAGE(1, 2, 1);
    VM2();          // T0 resident; T1.B0 (newest 2) may remain in flight
    BAR();

    // ---- main loop: iter i computes tiles 2i (d0, ph1-4) and 2i+1 (d1,
    // ph5-8); each tile = kk0:{mf0-3,+B | mf4-7} then kk1:{...}.
    for (int i = 0; i < 15; ++i) {
        const int T1 = 2 * i + 1, T2 = 2 * i + 2, T3 = 2 * i + 3;
        PHASE(0, 0, 0, 1, STAGE(1, 0, T1); STAGE(1, 3, T1));  BAR();
        PHASE(0, 0, 4, 0, STAGE(1, 1, T1));                   BAR();
        PHASE(0, 4, 0, 1, );                                  BAR();
        PHASE(0, 4, 4, 0, STAGE(0, 2, T2));            VM2(); BAR();
        PHASE(1, 0, 0, 1, STAGE(0, 3, T2));                   BAR();
        PHASE(1, 0, 4, 0, STAGE(0, 0, T2));                   BAR();
        PHASE(1, 4, 0, 1, STAGE(0, 1, T2));                   BAR();
        PHASE(1, 4, 4, 0, STAGE(1, 2, T3));            VM2(); BAR();
    }
    // ---- tail: tiles 30 (d0) / 31 (d1); only T31.{A0,A1,B1} left to stage.
    PHASE(0, 0, 0, 1, STAGE(1, 0, 31); STAGE(1, 3, 31));  BAR();
    PHASE(0, 0, 4, 0, STAGE(1, 1, 31));                   BAR();
    PHASE(0, 4, 0, 1, );                                  BAR();
    PHASE(0, 4, 4, 0, );                           VM0(); BAR();
    PHASE(1, 0, 0, 1, );                                  BAR();
    PHASE(1, 0, 4, 0, );                                  BAR();
    PHASE(1, 4, 0, 1, );                                  BAR();
    PHASE(1, 4, 4, 0, );

#undef PHASE
#undef STAGE
#undef BAR
#undef VM2
#undef VM0

    // ---- epilogue: bias + tanh, fp32 store.
    // C/D layout: col = lane&15, row = (lane>>4)*4 + reg (verified r1-r7).
    float bv[4];
#pragma unroll
    for (int nf = 0; nf < 4; ++nf)
        bv[nf] = bias[bn + wn * 64 + nf * 16 + lr];
#pragma unroll
    for (int mf = 0; mf < 8; ++mf) {
#pragma unroll
        for (int nf = 0; nf < 4; ++nf) {
            const int col = bn + wn * 64 + nf * 16 + lr;
#pragma unroll
            for (int r = 0; r < 4; ++r) {
                const int row = bm + wm * 128 + mf * 16 + lk * 4 + r;
                out[(size_t)row * N_GLOBAL + col] = fast_tanh(acc[mf][nf][r] + bv[nf]);
            }
        }
    }
}

// ---------------------------------------------------------------------------
// Fallback (ws too small): round-3 verified fused kernel (~169 us).
// ---------------------------------------------------------------------------
#define FNT 32
__global__ __launch_bounds__(256, 2)
void rnncell_fused(const float* __restrict__ x, const float* __restrict__ h,
                   const float* __restrict__ W, const float* __restrict__ bias,
                   float* __restrict__ out)
{
    __shared__ __align__(16) bf16_t As[2][128 * 64];
    __shared__ __align__(16) bf16_t Bs[2][128 * 64];

    const int tid = threadIdx.x;
    const int bid = blockIdx.x;
    const int bm = (bid >> 3) * 128;
    const int bn = (bid & 7) * 128;

    const int lane = tid & 63;
    const int wid  = tid >> 6;
    const int wr = (wid >> 1) * 64;
    const int wc = (wid & 1) * 64;
    const int lr = lane & 15;
    const int lk = lane >> 4;

    const int row0 = tid >> 3;
    const int sl0  = tid & 7;

    f32x4 acc[4][4];
#pragma unroll
    for (int i = 0; i < 4; ++i)
#pragma unroll
        for (int j = 0; j < 4; ++j)
            acc[i][j] = (f32x4){0.f, 0.f, 0.f, 0.f};

    float4 la[4][2], lb[4][2];

#define F_LOAD_A(T) do {                                                      \
    const int k0_ = (T) * 64;                                                 \
    const float* sA_ = (k0_ < 1024)                                           \
        ? (x + (size_t)bm * IN_STRIDE + k0_)                                  \
        : (h + (size_t)bm * IN_STRIDE + (k0_ - 1024));                        \
    _Pragma("unroll")                                                         \
    for (int i_ = 0; i_ < 4; ++i_) {                                          \
        const float* pa_ = sA_ + (size_t)(row0 + i_ * 32) * IN_STRIDE + sl0 * 8; \
        la[i_][0] = *(const float4*)(pa_);                                    \
        la[i_][1] = *(const float4*)(pa_ + 4);                                \
    }                                                                         \
} while (0)

#define F_LOAD_B(T) do {                                                      \
    const float* sB_ = W + (size_t)bn * K_GLOBAL + (T) * 64;                  \
    _Pragma("unroll")                                                         \
    for (int i_ = 0; i_ < 4; ++i_) {                                          \
        const float* pb_ = sB_ + (size_t)(row0 + i_ * 32) * K_GLOBAL + sl0 * 8; \
        lb[i_][0] = *(const float4*)(pb_);                                    \
        lb[i_][1] = *(const float4*)(pb_ + 4);                                \
    }                                                                         \
} while (0)

    F_LOAD_A(0);
    F_LOAD_B(0);

    for (int t = 0; t < FNT; ++t) {
        bf16_t* __restrict__ Ab = As[t & 1];
        bf16_t* __restrict__ Bb = Bs[t & 1];

#pragma unroll
        for (int i = 0; i < 4; ++i) {
            const int row = row0 + i * 32;
            const int ssl = sl0 ^ (row & 7);
            bf16x8 va;
            va[0] = (bf16_t)la[i][0].x; va[1] = (bf16_t)la[i][0].y;
            va[2] = (bf16_t)la[i][0].z; va[3] = (bf16_t)la[i][0].w;
            va[4] = (bf16_t)la[i][1].x; va[5] = (bf16_t)la[i][1].y;
            va[6] = (bf16_t)la[i][1].z; va[7] = (bf16_t)la[i][1].w;
            *(bf16x8*)(Ab + row * 64 + ssl * 8) = va;
        }
#pragma unroll
        for (int i = 0; i < 4; ++i) {
            const int row = row0 + i * 32;
            const int ssl = sl0 ^ (row & 7);
            bf16x8 vb;
            vb[0] = (bf16_t)lb[i][0].x; vb[1] = (bf16_t)lb[i][0].y;
            vb[2] = (bf16_t)lb[i][0].z; vb[3] = (bf16_t)lb[i][0].w;
            vb[4] = (bf16_t)lb[i][1].x; vb[5] = (bf16_t)lb[i][1].y;
            vb[6] = (bf16_t)lb[i][1].z; vb[7] = (bf16_t)lb[i][1].w;
            *(bf16x8*)(Bb + row * 64 + ssl * 8) = vb;
        }

        __syncthreads();

        if (t + 1 < FNT) F_LOAD_A(t + 1);

#pragma unroll
        for (int kk = 0; kk < 2; ++kk) {
            bf16x8 af[4], bfr[4];
#pragma unroll
            for (int mf = 0; mf < 4; ++mf) {
                const int row = wr + mf * 16 + lr;
                const int sl  = (kk * 4 + lk) ^ (row & 7);
                af[mf] = *(const bf16x8*)(Ab + row * 64 + sl * 8);
            }
#pragma unroll
            for (int nf = 0; nf < 4; ++nf) {
                const int row = wc + nf * 16 + lr;
                const int sl  = (kk * 4 + lk) ^ (row & 7);
                bfr[nf] = *(const bf16x8*)(Bb + row * 64 + sl * 8);
            }
#pragma unroll
            for (int mf = 0; mf < 4; ++mf)
#pragma unroll
                for (int nf = 0; nf < 4; ++nf)
                    acc[mf][nf] = __builtin_amdgcn_mfma_f32_16x16x32_bf16(
                        af[mf], bfr[nf], acc[mf][nf], 0, 0, 0);
        }

        if (t + 1 < FNT) F_LOAD_B(t + 1);
    }
#undef F_LOAD_A
#undef F_LOAD_B

    float bv[4];
#pragma unroll
    for (int nf = 0; nf < 4; ++nf)
        bv[nf] = bias[bn + wc + nf * 16 + lr];
#pragma unroll
    for (int mf = 0; mf < 4; ++mf) {
#pragma unroll
        for (int nf = 0; nf < 4; ++nf) {
            const int col = bn + wc + nf * 16 + lr;
#pragma unroll
            for (int r = 0; r < 4; ++r) {
                const int row = bm + wr + mf * 16 + lk * 4 + r;
                out[(size_t)row * N_GLOBAL + col] = fast_tanh(acc[mf][nf][r] + bv[nf]);
            }
        }
    }
}

extern "C" void kernel_launch(void* const* d_in, const int* in_sizes, int n_in,
                              void* d_out, int out_size, void* d_ws, size_t ws_size,
                              hipStream_t stream) {
    (void)in_sizes; (void)n_in; (void)out_size;
    const float* x = (const float*)d_in[0];
    const float* h = (const float*)d_in[1];
    const float* W = (const float*)d_in[2];
    const float* b = (const float*)d_in[3];
    float* out = (float*)d_out;

    const size_t need = ((size_t)M_GLOBAL + N_GLOBAL) * K_GLOBAL * sizeof(bf16_t);
    if (ws_size >= need) {
        bf16_t* XHb = (bf16_t*)d_ws;
        bf16_t* Wb  = XHb + (size_t)M_GLOBAL * K_GLOBAL;
        cvt_pass<<<2048, 256, 0, stream>>>(x, h, W, XHb, Wb);
        gemm8p<<<256, 512, 0, stream>>>(XHb, Wb, b, out);
    } else {
        rnncell_fused<<<1024, 256, 0, stream>>>(x, h, W, b, out);
    }
}

// Round 12
// 102.075 us; speedup vs baseline: 1.4284x; 1.0049x over previous
//
#include <hip/hip_runtime.h>
#include <hip/hip_bf16.h>

// RNN cell: out[B,N] = tanh( concat(x,hidden)[B,K] @ W^T[K,N] + b[N] )
// M=16384, N=1024, K=2048, fp32 in/out.
// Pass 1: fp32->bf16 cvt+concat into ws. Pass 2: 256x256 8-phase GEMM.
// Round-10 change vs r9: REMOVED the explicit lgkmcnt(0)+sched_barrier(0)
// before the MFMA cluster -- plain-load ds_reads are compiler-tracked and
// hipcc emits fine-grained lgkmcnt(N) waits (m97), letting each wave start
// MFMAs after its FIRST read lands (read-tail hides under MFMA). The full
// drain was serializing read-pipe and MFMA (1738 cyc/phase vs ~900 content).
// (Rounds 10/11 both died at container-connection setup -- source never
//  reached hardware. Third submission, identical source.)

typedef __bf16 bf16_t;
typedef __bf16 bf16x8 __attribute__((ext_vector_type(8)));
typedef float  f32x4  __attribute__((ext_vector_type(4)));

#define M_GLOBAL 16384
#define N_GLOBAL 1024
#define K_GLOBAL 2048
#define IN_STRIDE 1024
#define NT 32

__device__ __forceinline__ float fast_tanh(float v) {
    float e = __expf(2.0f * v);
    return 1.0f - 2.0f * __builtin_amdgcn_rcpf(e + 1.0f);
}

// ---------------------------------------------------------------------------
// Pass 1: cvt + concat (~6.4 TB/s; L3-warm on replay).
// ---------------------------------------------------------------------------
#define XH_UNITS ((long long)M_GLOBAL * K_GLOBAL / 8)
#define W_UNITS  ((long long)N_GLOBAL * K_GLOBAL / 8)

__global__ __launch_bounds__(256)
void cvt_pass(const float* __restrict__ x, const float* __restrict__ h,
              const float* __restrict__ W,
              bf16_t* __restrict__ XHb, bf16_t* __restrict__ Wb)
{
    const long long total = XH_UNITS + W_UNITS;
    for (long long u = (long long)blockIdx.x * 256 + threadIdx.x; u < total;
         u += (long long)gridDim.x * 256) {
        const float* src;
        bf16_t* dst;
        if (u < XH_UNITS) {
            const long long e = u * 8;
            const int row = (int)(e >> 11);
            const int col = (int)(e & 2047);
            src = (col < 1024) ? (x + (long long)row * IN_STRIDE + col)
                               : (h + (long long)row * IN_STRIDE + (col - 1024));
            dst = XHb + e;
        } else {
            const long long e = (u - XH_UNITS) * 8;
            src = W + e;
            dst = Wb + e;
        }
        const float4 v0 = *(const float4*)src;
        const float4 v1 = *(const float4*)(src + 4);
        bf16x8 o;
        o[0] = (bf16_t)v0.x; o[1] = (bf16_t)v0.y;
        o[2] = (bf16_t)v0.z; o[3] = (bf16_t)v0.w;
        o[4] = (bf16_t)v1.x; o[5] = (bf16_t)v1.y;
        o[6] = (bf16_t)v1.z; o[7] = (bf16_t)v1.w;
        *(bf16x8*)dst = o;
    }
}

// ---------------------------------------------------------------------------
// Pass 2: 256x256 8-phase GEMM, kk-major phases (r9 schedule, r10 waits).
// 512 threads = 8 waves (2M x 4N), per-wave output 128x64. BK=64.
// LDS: 2 dbuf x {A0,A1,B0,B1} 128x64 halves (16 KB each) = 128 KB.
// Swizzle (0 conflicts, verified r7/r9): slot s of row r holds k-slot
// s^(r&7); applied on global SOURCE (gload_lds writes linearly) + ds_read.
//
// Stage slots per iter i (T1=2i+1, T2=2i+2, T3=2i+3), gates VM2 @ph4, ph8:
//  ph1: T1.A0->d1, T1.B1->d1   ph2: T1.A1->d1   ph3: --
//  ph4: T2.B0->d0 [VM2]        ph5: T2.B1->d0   ph6: T2.A0->d0
//  ph7: T2.A1->d0              ph8: T3.B0->d1 [VM2]
// RAW/WAR audit unchanged from r9 (every stage drains >=2 phases before
// first read; every overwrite >=1 barrier-pair after last read).
// ---------------------------------------------------------------------------
__device__ __forceinline__ void gload_lds16(const bf16_t* g, bf16_t* l) {
    __builtin_amdgcn_global_load_lds(
        (const __attribute__((address_space(1))) void*)g,
        (__attribute__((address_space(3))) void*)l, 16, 0, 0);
}

__global__ __launch_bounds__(512, 2)
void gemm8p(const bf16_t* __restrict__ XHb, const bf16_t* __restrict__ Wb,
            const float* __restrict__ bias, float* __restrict__ out)
{
    __shared__ __align__(16) bf16_t lds[2 * 32768];   // 128 KB

    const int tid = threadIdx.x;
    // XCD-aware bijective remap (grid=256 = 8 XCDs x 32).
    const int xcd  = blockIdx.x & 7;
    const int lid  = xcd * 32 + (blockIdx.x >> 3);
    const int bm   = (lid & 63) * 256;
    const int bn   = (lid >> 6) * 256;

    const int lane = tid & 63;
    const int wid  = tid >> 6;
    const int wm = wid >> 2;          // 0..1 (M half)
    const int wn = wid & 3;           // 0..3 (N quarter)
    const int lr = lane & 15;
    const int lk = lane >> 4;
    const int s7 = lr & 7;

    // staging: half-tile = 128 rows x 64 cols; wave stages 2 chunks of 8
    // rows; lane covers row srow, source col pre-swizzled.
    const int srow = lane >> 3;
    const int scol = ((lane & 7) ^ srow) * 8;
    const int c0   = wid * 2;
    const bf16_t* aS = XHb + (size_t)(bm + c0 * 8 + srow) * K_GLOBAL + scol;
    const bf16_t* bS = Wb  + (size_t)(bn + c0 * 8 + srow) * K_GLOBAL + scol;

    // frag-read bases (elems): parts A0,A1,B0,B1 at part*8192 within dbuf.
    const int aRd = wm * 8192 + lr * 64;
    const int bRd = (2 + (wn >> 1)) * 8192 + ((wn & 1) * 64 + lr) * 64;

    f32x4 acc[8][4];
#pragma unroll
    for (int i = 0; i < 8; ++i)
#pragma unroll
        for (int j = 0; j < 4; ++j)
            acc[i][j] = (f32x4){0.f, 0.f, 0.f, 0.f};

#define STAGE(D, PART, T) {                                                   \
    const bf16_t* g_ = (((PART) < 2) ? aS : bS)                               \
        + (size_t)(((PART) & 1) * 128) * K_GLOBAL + (T) * 64;                 \
    bf16_t* l_ = lds + (D) * 32768 + (PART) * 8192 + c0 * 512;                \
    gload_lds16(g_, l_);                                                      \
    gload_lds16(g_ + (size_t)8 * K_GLOBAL, l_ + 512);                         \
}

#define BAR() { asm volatile("" ::: "memory");                                \
                __builtin_amdgcn_s_barrier();                                 \
                asm volatile("" ::: "memory"); }
#define VM2() asm volatile("s_waitcnt vmcnt(2)" ::: "memory")
#define VM0() asm volatile("s_waitcnt vmcnt(0)" ::: "memory")

// One phase: kk-slice SLK, mf-half M0. Reads 4 A-frags (+4 B-frags into
// persistent bq if READB), stages, barrier, then setprio-wrapped 16
// independent MFMA. NO explicit lgkm drain: compiler emits fine-grained
// lgkmcnt(N) waits so each wave's MFMA start overlaps its read tail and
// other waves' LDS drain (r10 change).
#define PHASE(DB, SLK, M0, READB, ...) {                                      \
    const int dbo_ = (DB) * 32768;                                            \
    const int sl_  = (((SLK) + lk) ^ s7) * 8;                                 \
    if (READB) {                                                              \
        _Pragma("unroll")                                                     \
        for (int nf_ = 0; nf_ < 4; ++nf_)                                     \
            bq[nf_] = *(const bf16x8*)(lds + dbo_ + bRd + nf_ * 1024 + sl_);  \
    }                                                                         \
    bf16x8 a0_ = *(const bf16x8*)(lds + dbo_ + aRd + ((M0) + 0) * 1024 + sl_); \
    bf16x8 a1_ = *(const bf16x8*)(lds + dbo_ + aRd + ((M0) + 1) * 1024 + sl_); \
    bf16x8 a2_ = *(const bf16x8*)(lds + dbo_ + aRd + ((M0) + 2) * 1024 + sl_); \
    bf16x8 a3_ = *(const bf16x8*)(lds + dbo_ + aRd + ((M0) + 3) * 1024 + sl_); \
    __VA_ARGS__;                                                              \
    asm volatile("" ::: "memory");                                            \
    __builtin_amdgcn_s_barrier();                                             \
    __builtin_amdgcn_s_setprio(1);                                            \
    _Pragma("unroll")                                                         \
    for (int nf_ = 0; nf_ < 4; ++nf_) {                                       \
        acc[(M0) + 0][nf_] = __builtin_amdgcn_mfma_f32_16x16x32_bf16(         \
            a0_, bq[nf_], acc[(M0) + 0][nf_], 0, 0, 0);                       \
        acc[(M0) + 1][nf_] = __builtin_amdgcn_mfma_f32_16x16x32_bf16(         \
            a1_, bq[nf_], acc[(M0) + 1][nf_], 0, 0, 0);                       \
        acc[(M0) + 2][nf_] = __builtin_amdgcn_mfma_f32_16x16x32_bf16(         \
            a2_, bq[nf_], acc[(M0) + 2][nf_], 0, 0, 0);                       \
        acc[(M0) + 3][nf_] = __builtin_amdgcn_mfma_f32_16x16x32_bf16(         \
            a3_, bq[nf_], acc[(M0) + 3][nf_], 0, 0, 0);                       \
    }                                                                         \
    __builtin_amdgcn_s_setprio(0);                                            \
}

    bf16x8 bq[4];

    // ---- prologue: T0 all 4 halves -> d0; T1.B0 -> d1 (10 loads).
    STAGE(0, 0, 0); STAGE(0, 1, 0); STAGE(0, 2, 0); STAGE(0, 3, 0);
    STAGE(1, 2, 1);
    VM2();          // T0 resident; T1.B0 (newest 2) may remain in flight
    BAR();

    // ---- main loop: iter i computes tiles 2i (d0, ph1-4) and 2i+1 (d1,
    // ph5-8); each tile = kk0:{mf0-3,+B | mf4-7} then kk1:{...}.
    for (int i = 0; i < 15; ++i) {
        const int T1 = 2 * i + 1, T2 = 2 * i + 2, T3 = 2 * i + 3;
        PHASE(0, 0, 0, 1, STAGE(1, 0, T1); STAGE(1, 3, T1));  BAR();
        PHASE(0, 0, 4, 0, STAGE(1, 1, T1));                   BAR();
        PHASE(0, 4, 0, 1, );                                  BAR();
        PHASE(0, 4, 4, 0, STAGE(0, 2, T2));            VM2(); BAR();
        PHASE(1, 0, 0, 1, STAGE(0, 3, T2));                   BAR();
        PHASE(1, 0, 4, 0, STAGE(0, 0, T2));                   BAR();
        PHASE(1, 4, 0, 1, STAGE(0, 1, T2));                   BAR();
        PHASE(1, 4, 4, 0, STAGE(1, 2, T3));            VM2(); BAR();
    }
    // ---- tail: tiles 30 (d0) / 31 (d1); only T31.{A0,A1,B1} left to stage.
    PHASE(0, 0, 0, 1, STAGE(1, 0, 31); STAGE(1, 3, 31));  BAR();
    PHASE(0, 0, 4, 0, STAGE(1, 1, 31));                   BAR();
    PHASE(0, 4, 0, 1, );                                  BAR();
    PHASE(0, 4, 4, 0, );                           VM0(); BAR();
    PHASE(1, 0, 0, 1, );                                  BAR();
    PHASE(1, 0, 4, 0, );                                  BAR();
    PHASE(1, 4, 0, 1, );                                  BAR();
    PHASE(1, 4, 4, 0, );

#undef PHASE
#undef STAGE
#undef BAR
#undef VM2
#undef VM0

    // ---- epilogue: bias + tanh, fp32 store.
    // C/D layout: col = lane&15, row = (lane>>4)*4 + reg (verified r1-r9).
    float bv[4];
#pragma unroll
    for (int nf = 0; nf < 4; ++nf)
        bv[nf] = bias[bn + wn * 64 + nf * 16 + lr];
#pragma unroll
    for (int mf = 0; mf < 8; ++mf) {
#pragma unroll
        for (int nf = 0; nf < 4; ++nf) {
            const int col = bn + wn * 64 + nf * 16 + lr;
#pragma unroll
            for (int r = 0; r < 4; ++r) {
                const int row = bm + wm * 128 + mf * 16 + lk * 4 + r;
                out[(size_t)row * N_GLOBAL + col] = fast_tanh(acc[mf][nf][r] + bv[nf]);
            }
        }
    }
}

// ---------------------------------------------------------------------------
// Fallback (ws too small): round-3 verified fused kernel (~169 us).
// ---------------------------------------------------------------------------
#define FNT 32
__global__ __launch_bounds__(256, 2)
void rnncell_fused(const float* __restrict__ x, const float* __restrict__ h,
                   const float* __restrict__ W, const float* __restrict__ bias,
                   float* __restrict__ out)
{
    __shared__ __align__(16) bf16_t As[2][128 * 64];
    __shared__ __align__(16) bf16_t Bs[2][128 * 64];

    const int tid = threadIdx.x;
    const int bid = blockIdx.x;
    const int bm = (bid >> 3) * 128;
    const int bn = (bid & 7) * 128;

    const int lane = tid & 63;
    const int wid  = tid >> 6;
    const int wr = (wid >> 1) * 64;
    const int wc = (wid & 1) * 64;
    const int lr = lane & 15;
    const int lk = lane >> 4;

    const int row0 = tid >> 3;
    const int sl0  = tid & 7;

    f32x4 acc[4][4];
#pragma unroll
    for (int i = 0; i < 4; ++i)
#pragma unroll
        for (int j = 0; j < 4; ++j)
            acc[i][j] = (f32x4){0.f, 0.f, 0.f, 0.f};

    float4 la[4][2], lb[4][2];

#define F_LOAD_A(T) do {                                                      \
    const int k0_ = (T) * 64;                                                 \
    const float* sA_ = (k0_ < 1024)                                           \
        ? (x + (size_t)bm * IN_STRIDE + k0_)                                  \
        : (h + (size_t)bm * IN_STRIDE + (k0_ - 1024));                        \
    _Pragma("unroll")                                                         \
    for (int i_ = 0; i_ < 4; ++i_) {                                          \
        const float* pa_ = sA_ + (size_t)(row0 + i_ * 32) * IN_STRIDE + sl0 * 8; \
        la[i_][0] = *(const float4*)(pa_);                                    \
        la[i_][1] = *(const float4*)(pa_ + 4);                                \
    }                                                                         \
} while (0)

#define F_LOAD_B(T) do {                                                      \
    const float* sB_ = W + (size_t)bn * K_GLOBAL + (T) * 64;                  \
    _Pragma("unroll")                                                         \
    for (int i_ = 0; i_ < 4; ++i_) {                                          \
        const float* pb_ = sB_ + (size_t)(row0 + i_ * 32) * K_GLOBAL + sl0 * 8; \
        lb[i_][0] = *(const float4*)(pb_);                                    \
        lb[i_][1] = *(const float4*)(pb_ + 4);                                \
    }                                                                         \
} while (0)

    F_LOAD_A(0);
    F_LOAD_B(0);

    for (int t = 0; t < FNT; ++t) {
        bf16_t* __restrict__ Ab = As[t & 1];
        bf16_t* __restrict__ Bb = Bs[t & 1];

#pragma unroll
        for (int i = 0; i < 4; ++i) {
            const int row = row0 + i * 32;
            const int ssl = sl0 ^ (row & 7);
            bf16x8 va;
            va[0] = (bf16_t)la[i][0].x; va[1] = (bf16_t)la[i][0].y;
            va[2] = (bf16_t)la[i][0].z; va[3] = (bf16_t)la[i][0].w;
            va[4] = (bf16_t)la[i][1].x; va[5] = (bf16_t)la[i][1].y;
            va[6] = (bf16_t)la[i][1].z; va[7] = (bf16_t)la[i][1].w;
            *(bf16x8*)(Ab + row * 64 + ssl * 8) = va;
        }
#pragma unroll
        for (int i = 0; i < 4; ++i) {
            const int row = row0 + i * 32;
            const int ssl = sl0 ^ (row & 7);
            bf16x8 vb;
            vb[0] = (bf16_t)lb[i][0].x; vb[1] = (bf16_t)lb[i][0].y;
            vb[2] = (bf16_t)lb[i][0].z; vb[3] = (bf16_t)lb[i][0].w;
            vb[4] = (bf16_t)lb[i][1].x; vb[5] = (bf16_t)lb[i][1].y;
            vb[6] = (bf16_t)lb[i][1].z; vb[7] = (bf16_t)lb[i][1].w;
            *(bf16x8*)(Bb + row * 64 + ssl * 8) = vb;
        }

        __syncthreads();

        if (t + 1 < FNT) F_LOAD_A(t + 1);

#pragma unroll
        for (int kk = 0; kk < 2; ++kk) {
            bf16x8 af[4], bfr[4];
#pragma unroll
            for (int mf = 0; mf < 4; ++mf) {
                const int row = wr + mf * 16 + lr;
                const int sl  = (kk * 4 + lk) ^ (row & 7);
                af[mf] = *(const bf16x8*)(Ab + row * 64 + sl * 8);
            }
#pragma unroll
            for (int nf = 0; nf < 4; ++nf) {
                const int row = wc + nf * 16 + lr;
                const int sl  = (kk * 4 + lk) ^ (row & 7);
                bfr[nf] = *(const bf16x8*)(Bb + row * 64 + sl * 8);
            }
#pragma unroll
            for (int mf = 0; mf < 4; ++mf)
#pragma unroll
                for (int nf = 0; nf < 4; ++nf)
                    acc[mf][nf] = __builtin_amdgcn_mfma_f32_16x16x32_bf16(
                        af[mf], bfr[nf], acc[mf][nf], 0, 0, 0);
        }

        if (t + 1 < FNT) F_LOAD_B(t + 1);
    }
#undef F_LOAD_A
#undef F_LOAD_B

    float bv[4];
#pragma unroll
    for (int nf = 0; nf < 4; ++nf)
        bv[nf] = bias[bn + wc + nf * 16 + lr];
#pragma unroll
    for (int mf = 0; mf < 4; ++mf) {
#pragma unroll
        for (int nf = 0; nf < 4; ++nf) {
            const int col = bn + wc + nf * 16 + lr;
#pragma unroll
            for (int r = 0; r < 4; ++r) {
                const int row = bm + wr + mf * 16 + lk * 4 + r;
                out[(size_t)row * N_GLOBAL + col] = fast_tanh(acc[mf][nf][r] + bv[nf]);
            }
        }
    }
}

extern "C" void kernel_launch(void* const* d_in, const int* in_sizes, int n_in,
                              void* d_out, int out_size, void* d_ws, size_t ws_size,
                              hipStream_t stream) {
    (void)in_sizes; (void)n_in; (void)out_size;
    const float* x = (const float*)d_in[0];
    const float* h = (const float*)d_in[1];
    const float* W = (const float*)d_in[2];
    const float* b = (const float*)d_in[3];
    float* out = (float*)d_out;

    const size_t need = ((size_t)M_GLOBAL + N_GLOBAL) * K_GLOBAL * sizeof(bf16_t);
    if (ws_size >= need) {
        bf16_t* XHb = (bf16_t*)d_ws;
        bf16_t* Wb  = XHb + (size_t)M_GLOBAL * K_GLOBAL;
        cvt_pass<<<2048, 256, 0, stream>>>(x, h, W, XHb, Wb);
        gemm8p<<<256, 512, 0, stream>>>(XHb, Wb, b, out);
    } else {
        rnncell_fused<<<1024, 256, 0, stream>>>(x, h, W, b, out);
    }
}